// Round 6
// baseline (344.743 us; speedup 1.0000x reference)
//
#include <hip/hip_runtime.h>
#include <hip/hip_bf16.h>

// ParamTable: idx = base-2 encoding of 16-wide x_pa row (MSB first),
// p = params[idx] (65536 x 2 f32), outputs concatenated:
// out[0..B) = col0, out[B..2B) = col1.
//
// *** DIAGNOSTIC ROUND: body executed PASSES=4 times (idempotent) so the
// kernel dispatch exceeds the rocprof top-5 cutoff (~79us of harness fills)
// and we finally see per-dispatch dur/FETCH/WRITE/hbm_gbps for our access
// pattern. T_kernel ~= dur/4. REVERT to PASSES=1 next round. ***

typedef int v4i __attribute__((ext_vector_type(4)));

constexpr int ROWS_PER_THREAD = 4;
constexpr int BLOCK = 256;
constexpr int TILE = BLOCK * ROWS_PER_THREAD;  // 1024 rows per block
constexpr int PASSES = 4;                      // DIAGNOSTIC; set to 1 to ship

__device__ __forceinline__ unsigned encode_idx(v4i a0, v4i a1, v4i a2, v4i a3) {
    return ((unsigned)a0.x << 15) | ((unsigned)a0.y << 14) |
           ((unsigned)a0.z << 13) | ((unsigned)a0.w << 12) |
           ((unsigned)a1.x << 11) | ((unsigned)a1.y << 10) |
           ((unsigned)a1.z << 9)  | ((unsigned)a1.w << 8)  |
           ((unsigned)a2.x << 7)  | ((unsigned)a2.y << 6)  |
           ((unsigned)a2.z << 5)  | ((unsigned)a2.w << 4)  |
           ((unsigned)a3.x << 3)  | ((unsigned)a3.y << 2)  |
           ((unsigned)a3.z << 1)  |  (unsigned)a3.w;
}

__global__ __launch_bounds__(BLOCK) void paramtable_gather_kernel(
    const int* __restrict__ x_pa,      // [B,16] values in {0,1}
    const float* __restrict__ params,  // [65536, 2]
    float* __restrict__ out,           // [2*B]
    int B) {
    int base = blockIdx.x * TILE + threadIdx.x;

#pragma unroll 1
    for (int pass = 0; pass < PASSES; ++pass) {
        unsigned idx[ROWS_PER_THREAD];
        bool     ok[ROWS_PER_THREAD];

        // Phase 1: stream the 4 rows (independent 64B loads -> 4 idx values)
#pragma unroll
        for (int j = 0; j < ROWS_PER_THREAD; ++j) {
            int b = base + j * BLOCK;
            ok[j] = (b < B);
            if (ok[j]) {
                const v4i* row = reinterpret_cast<const v4i*>(x_pa) + (size_t)b * 4;
                v4i a0 = __builtin_nontemporal_load(row + 0);
                v4i a1 = __builtin_nontemporal_load(row + 1);
                v4i a2 = __builtin_nontemporal_load(row + 2);
                v4i a3 = __builtin_nontemporal_load(row + 3);
                idx[j] = encode_idx(a0, a1, a2, a3);
            }
        }

        // Phase 2: 4 independent table gathers in flight, then streamed stores
        float2 p[ROWS_PER_THREAD];
#pragma unroll
        for (int j = 0; j < ROWS_PER_THREAD; ++j) {
            if (ok[j]) p[j] = reinterpret_cast<const float2*>(params)[idx[j]];
        }
#pragma unroll
        for (int j = 0; j < ROWS_PER_THREAD; ++j) {
            if (ok[j]) {
                int b = base + j * BLOCK;
                __builtin_nontemporal_store(p[j].x, out + b);
                __builtin_nontemporal_store(p[j].y, out + B + b);
            }
        }

        // Prevent cross-pass CSE/redundant-load-elimination so each pass
        // re-issues the full memory traffic (diagnostic passes must be real).
        asm volatile("" ::: "memory");
    }
}

extern "C" void kernel_launch(void* const* d_in, const int* in_sizes, int n_in,
                              void* d_out, int out_size, void* d_ws, size_t ws_size,
                              hipStream_t stream) {
    // setup_inputs order: x [B] (unused), x_pa [B*16], params [65536*2]
    const int*   x_pa   = (const int*)d_in[1];
    const float* params = (const float*)d_in[2];
    float*       out    = (float*)d_out;

    int B = in_sizes[0];  // x has B elements

    int blocks = (B + TILE - 1) / TILE;
    paramtable_gather_kernel<<<blocks, BLOCK, 0, stream>>>(x_pa, params, out, B);
}

// Round 7
// 194.297 us; speedup vs baseline: 1.7743x; 1.7743x over previous
//
#include <hip/hip_runtime.h>
#include <hip/hip_bf16.h>

// ParamTable: idx = base-2 encoding of 16-wide x_pa row (MSB first),
// p = params[idx] (65536 x 2 f32), outputs concatenated:
// out[0..B) = col0, out[B..2B) = col1.
//
// R6 diagnostic: old one-row-per-thread layout had 64 distinct lines per
// load instruction (lane stride 64B) -> TA transaction-limited at ~46us/pass
// (hbm 22%, VALU 3%, occupancy 64% -- everything idle). This version loads
// lane-CONTIGUOUS 16B chunks (wave = 1KiB = 16 rows, 16 transactions/inst,
// 4x fewer) and assembles each row's 16-bit index across its 4-lane quad
// with two quad-local __shfl_xor (DPP, register-only). Duplicate gathers/
// stores within a quad hit the same cache line -> coalesced, no extra
// transactions.

typedef int v4i __attribute__((ext_vector_type(4)));

constexpr int BLOCK = 256;           // 4 waves
constexpr int ROWS_PER_BLOCK = 256;  // 64 rows per wave (4 rounds x 16 rows)

__global__ __launch_bounds__(BLOCK) void paramtable_gather_kernel(
    const int* __restrict__ x_pa,      // [B,16] values in {0,1}
    const float* __restrict__ params,  // [65536, 2]
    float* __restrict__ out,           // [2*B]
    int B) {
    const int lane = threadIdx.x & 63;
    const int wave = threadIdx.x >> 6;                       // 0..3
    const int rowBase = blockIdx.x * ROWS_PER_BLOCK + wave * 64;
    if (rowBase >= B) return;                                // uniform

    const int m = lane >> 2;                                 // quad id: row within 16-row group
    const int shift = 12 - ((lane & 3) << 2);                // quarter q -> bit position

    // This wave's 64 rows start at 16B-chunk index rowBase*4.
    const v4i* chunks = reinterpret_cast<const v4i*>(x_pa) + (size_t)rowBase * 4;

    unsigned idx[4];
#pragma unroll
    for (int k = 0; k < 4; ++k) {
        // lane-contiguous: round k covers chunks [k*64, k*64+64) = rows k*16..k*16+15
        v4i c = __builtin_nontemporal_load(chunks + k * 64 + lane);
        unsigned n = ((unsigned)c.x << 3) | ((unsigned)c.y << 2) |
                     ((unsigned)c.z << 1) |  (unsigned)c.w;
        unsigned partial = n << shift;
        // OR-reduce across the 4-lane quad (xor 1, xor 2 -> DPP quad_perm)
        unsigned p1 = partial | __shfl_xor(partial, 1);
        idx[k] = p1 | __shfl_xor(p1, 2);
    }

    // 4 independent table gathers in flight (quad-duplicated -> same line,
    // coalesced by the TA; params stays L2-hot, no nt hint here).
    float2 p[4];
#pragma unroll
    for (int k = 0; k < 4; ++k) {
        p[k] = reinterpret_cast<const float2*>(params)[idx[k]];
    }

    // Stores: 16 distinct dwords per instruction (quad-duplicated, same
    // value -> idempotent, one 64B line per instruction).
#pragma unroll
    for (int k = 0; k < 4; ++k) {
        int b = rowBase + k * 16 + m;
        __builtin_nontemporal_store(p[k].x, out + b);
        __builtin_nontemporal_store(p[k].y, out + B + b);
    }
}

extern "C" void kernel_launch(void* const* d_in, const int* in_sizes, int n_in,
                              void* d_out, int out_size, void* d_ws, size_t ws_size,
                              hipStream_t stream) {
    // setup_inputs order: x [B] (unused), x_pa [B*16], params [65536*2]
    const int*   x_pa   = (const int*)d_in[1];
    const float* params = (const float*)d_in[2];
    float*       out    = (float*)d_out;

    int B = in_sizes[0];  // x has B elements

    int blocks = (B + ROWS_PER_BLOCK - 1) / ROWS_PER_BLOCK;
    paramtable_gather_kernel<<<blocks, BLOCK, 0, stream>>>(x_pa, params, out, B);
}